// Round 3
// baseline (138.261 us; speedup 1.0000x reference)
//
#include <hip/hip_runtime.h>

// OnlineTripletLoss: emb (8192,512) f32, triplets (131072,3) int32.
// Strategy: shard D into 8 chunks of 64 floats; chunk c processed only by
// blocks with blockIdx%8==c -> lands on XCD c (round-robin dispatch), whose
// 2 MB sub-table stays L2-resident. All gather traffic becomes L2 hits.

#define MARGIN_INV (1.0f / 0.7f)
#define D 512
#define NCHUNK 8
#define CHUNKF 64                       // floats per chunk (256 B)

constexpr int P1_BLOCKS  = 2048;
constexpr int P1_THREADS = 256;         // 4 waves
constexpr int SLICES     = P1_BLOCKS / NCHUNK;   // 256 triplet slices

// ---------------- pass 1: per-chunk partial dots ----------------
__global__ __launch_bounds__(P1_THREADS) void p1_chunk_dots(
    const float* __restrict__ emb,
    const int* __restrict__ trip,
    int T,
    float2* __restrict__ part /* [NCHUNK][T] */) {

    const int lane  = threadIdx.x & 63;
    const int wave  = threadIdx.x >> 6;
    const int c     = blockIdx.x & (NCHUNK - 1);   // chunk == XCD (assumed)
    const int slice = blockIdx.x >> 3;

    const int perSlice = T / SLICES;               // 512
    const int perWave  = perSlice / 4;             // 128
    const int t0       = slice * perSlice + wave * perWave;

    const int  l5  = lane & 31;
    const bool hi  = lane >= 32;
    const int  col = c * CHUNKF + l5 * 2;          // float2 per lane, 32 lanes = 64 floats

    float2* __restrict__ outp = part + (size_t)c * T;

    for (int i = 0; i < perWave; ++i) {
        const int t = t0 + i;
        if (t >= T) break;
        const int i0 = trip[3 * t + 0];
        const int i1 = trip[3 * t + 1];
        const int i2 = trip[3 * t + 2];

        const float2 a = *(const float2*)(emb + (size_t)i0 * D + col);
        const int    ib = hi ? i2 : i1;
        const float2 b = *(const float2*)(emb + (size_t)ib * D + col);

        float s = a.x * b.x + a.y * b.y;
        // butterfly within each 32-lane half: low half -> ap, high half -> an
        s += __shfl_xor(s, 16);
        s += __shfl_xor(s, 8);
        s += __shfl_xor(s, 4);
        s += __shfl_xor(s, 2);
        s += __shfl_xor(s, 1);

        const float an = __shfl(s, 32);            // lane 32's sum -> all lanes
        if (lane == 0) outp[t] = make_float2(s, an);
    }
}

// ---------------- pass 2: combine chunks, clip, exp, block-reduce ----------------
constexpr int P2_BLOCKS  = 512;
constexpr int P2_THREADS = 256;

__global__ __launch_bounds__(P2_THREADS) void p2_combine(
    const float2* __restrict__ part, int T,
    float* __restrict__ bpart /* [P2_BLOCKS*3] */) {

    const int t = blockIdx.x * P2_THREADS + threadIdx.x;

    float ap = 0.f, an = 0.f;
    if (t < T) {
        #pragma unroll
        for (int c = 0; c < NCHUNK; ++c) {
            const float2 v = part[(size_t)c * T + t];
            ap += v.x; an += v.y;
        }
    }
    ap = fminf(fmaxf(ap, -1.0f), 1.0f);
    an = fminf(fmaxf(an, -1.0f), 1.0f);

    float s_loss = (t < T) ? __expf((an - ap) * MARGIN_INV) : 0.f;
    float s_ap   = (t < T) ? (1.0f - ap) : 0.f;
    float s_an   = (t < T) ? (1.0f - an) : 0.f;

    #pragma unroll
    for (int off = 32; off; off >>= 1) {
        s_loss += __shfl_xor(s_loss, off);
        s_ap   += __shfl_xor(s_ap, off);
        s_an   += __shfl_xor(s_an, off);
    }
    __shared__ float red[4][3];
    const int lane = threadIdx.x & 63, wave = threadIdx.x >> 6;
    if (lane == 0) { red[wave][0] = s_loss; red[wave][1] = s_ap; red[wave][2] = s_an; }
    __syncthreads();
    if (threadIdx.x == 0) {
        float a = 0.f, b = 0.f, cc = 0.f;
        #pragma unroll
        for (int w = 0; w < 4; ++w) { a += red[w][0]; b += red[w][1]; cc += red[w][2]; }
        bpart[blockIdx.x * 3 + 0] = a;
        bpart[blockIdx.x * 3 + 1] = b;
        bpart[blockIdx.x * 3 + 2] = cc;
    }
}

// ---------------- pass 3: final reduce ----------------
__global__ __launch_bounds__(256) void p3_final(
    const float* __restrict__ bpart, int nblocks, int T,
    float* __restrict__ out) {

    const int tid = threadIdx.x;
    float a = 0.f, b = 0.f, c = 0.f;
    for (int i = tid; i < nblocks; i += 256) {
        a += bpart[3 * i + 0];
        b += bpart[3 * i + 1];
        c += bpart[3 * i + 2];
    }
    #pragma unroll
    for (int off = 32; off; off >>= 1) {
        a += __shfl_xor(a, off);
        b += __shfl_xor(b, off);
        c += __shfl_xor(c, off);
    }
    __shared__ float red[4][3];
    const int lane = tid & 63, wave = tid >> 6;
    if (lane == 0) { red[wave][0] = a; red[wave][1] = b; red[wave][2] = c; }
    __syncthreads();
    if (tid == 0) {
        float A = 0.f, B = 0.f, C = 0.f;
        #pragma unroll
        for (int w = 0; w < 4; ++w) { A += red[w][0]; B += red[w][1]; C += red[w][2]; }
        const float inv = 1.0f / (float)T;
        out[0] = A * inv;
        out[1] = B * inv;
        out[2] = C * inv;
    }
}

// ---------------- fallback (proven R2 kernel) ----------------
constexpr int FB_BLOCKS  = 2048;
constexpr int FB_THREADS = 256;
constexpr int FB_WPB     = FB_THREADS / 64;
constexpr int FB_TOTALW  = FB_BLOCKS * FB_WPB;

__global__ __launch_bounds__(FB_THREADS) void fb_main(
    const float* __restrict__ emb, const int* __restrict__ trip, int T,
    float* __restrict__ partials) {

    const int lane  = threadIdx.x & 63;
    const int wave  = threadIdx.x >> 6;
    const int gwave = blockIdx.x * FB_WPB + wave;

    float s_loss = 0.f, s_ap = 0.f, s_an = 0.f;
    for (int t = gwave; t < T; t += FB_TOTALW) {
        const int i0 = trip[3 * t + 0];
        const int i1 = trip[3 * t + 1];
        const int i2 = trip[3 * t + 2];
        const float4* a4 = (const float4*)(emb + (size_t)i0 * D) + (lane << 1);
        const float4* p4 = (const float4*)(emb + (size_t)i1 * D) + (lane << 1);
        const float4* n4 = (const float4*)(emb + (size_t)i2 * D) + (lane << 1);
        const float4 a0 = a4[0], a1 = a4[1];
        const float4 p0 = p4[0], p1 = p4[1];
        const float4 n0 = n4[0], n1 = n4[1];
        float ap = a0.x*p0.x + a0.y*p0.y + a0.z*p0.z + a0.w*p0.w
                 + a1.x*p1.x + a1.y*p1.y + a1.z*p1.z + a1.w*p1.w;
        float an = a0.x*n0.x + a0.y*n0.y + a0.z*n0.z + a0.w*n0.w
                 + a1.x*n1.x + a1.y*n1.y + a1.z*n1.z + a1.w*n1.w;
        #pragma unroll
        for (int off = 32; off; off >>= 1) { ap += __shfl_xor(ap, off); an += __shfl_xor(an, off); }
        ap = fminf(fmaxf(ap, -1.0f), 1.0f);
        an = fminf(fmaxf(an, -1.0f), 1.0f);
        s_loss += __expf((an - ap) * MARGIN_INV);
        s_ap   += 1.0f - ap;
        s_an   += 1.0f - an;
    }
    __shared__ float red[FB_WPB][3];
    if (lane == 0) { red[wave][0] = s_loss; red[wave][1] = s_ap; red[wave][2] = s_an; }
    __syncthreads();
    if (threadIdx.x == 0) {
        float a = 0.f, b = 0.f, c = 0.f;
        #pragma unroll
        for (int w = 0; w < FB_WPB; ++w) { a += red[w][0]; b += red[w][1]; c += red[w][2]; }
        partials[blockIdx.x * 3 + 0] = a;
        partials[blockIdx.x * 3 + 1] = b;
        partials[blockIdx.x * 3 + 2] = c;
    }
}

extern "C" void kernel_launch(void* const* d_in, const int* in_sizes, int n_in,
                              void* d_out, int out_size, void* d_ws, size_t ws_size,
                              hipStream_t stream) {
    const float* emb  = (const float*)d_in[0];
    const int*   trip = (const int*)d_in[1];
    float* out = (float*)d_out;
    const int T = in_sizes[1] / 3;     // 131072

    const size_t partBytes = (size_t)NCHUNK * T * sizeof(float2);   // 8 MB
    const size_t needed = partBytes + P2_BLOCKS * 3 * sizeof(float);

    if (ws_size >= needed) {
        float2* part  = (float2*)d_ws;
        float*  bpart = (float*)((char*)d_ws + partBytes);
        p1_chunk_dots<<<P1_BLOCKS, P1_THREADS, 0, stream>>>(emb, trip, T, part);
        p2_combine<<<P2_BLOCKS, P2_THREADS, 0, stream>>>(part, T, bpart);
        p3_final<<<1, 256, 0, stream>>>(bpart, P2_BLOCKS, T, out);
    } else {
        float* partials = (float*)d_ws;   // 24 KB
        fb_main<<<FB_BLOCKS, FB_THREADS, 0, stream>>>(emb, trip, T, partials);
        p3_final<<<1, 256, 0, stream>>>(partials, FB_BLOCKS, T, out);
    }
}

// Round 4
// 49.285 us; speedup vs baseline: 2.8053x; 2.8053x over previous
//
#include <hip/hip_runtime.h>

// OnlineTripletLoss: emb (8192,512) f32, triplets (131072,3) int32.
// D sharded into 8 chunks of 64 floats; chunk c handled by blocks with
// blockIdx%8==c -> per-XCD 2MB sub-table stays L2-resident (proven R3:
// FETCH_SIZE 310MB -> 14MB). This round: restructure p1 for parallelism —
// 4 lanes/triplet x 16 floats/lane, 16 triplets per wave-iteration,
// 2-step shuffle reduce (was 1 triplet/wave-iter + 6-step reduce).

#define MARGIN_INV (1.0f / 0.7f)
#define D 512
#define NCHUNK 8
#define CHUNKF 64

constexpr int P1_BLOCKS  = 2048;
constexpr int P1_THREADS = 256;        // 4 waves
constexpr int WPB        = P1_THREADS / 64;
constexpr int BLK_PER_CHUNK = P1_BLOCKS / NCHUNK;          // 256
constexpr int WAVES_PER_CHUNK = BLK_PER_CHUNK * WPB;       // 1024

__device__ __forceinline__ float dot4(float4 a, float4 b) {
    return a.x * b.x + a.y * b.y + a.z * b.z + a.w * b.w;
}

// ---------------- pass 1: per-chunk partial dots ----------------
__global__ __launch_bounds__(P1_THREADS) void p1_chunk_dots(
    const float* __restrict__ emb,
    const int* __restrict__ trip,
    int T,
    float2* __restrict__ part /* [NCHUNK][T] */) {

    const int lane  = threadIdx.x & 63;
    const int wave  = threadIdx.x >> 6;
    const int sub   = lane & 3;        // lane within triplet group
    const int g     = lane >> 2;       // triplet group 0..15
    const int c     = blockIdx.x & (NCHUNK - 1);
    const int slice = blockIdx.x >> 3; // 0..255

    const int perWave = (T + WAVES_PER_CHUNK - 1) / WAVES_PER_CHUNK;  // 128
    const int t0 = (slice * WPB + wave) * perWave;

    // lane's 4 float4 slots: col + {0,16,32,48} floats; 4 lanes cover 64B segs
    const float* __restrict__ embc = emb + c * CHUNKF + sub * 4;
    float2* __restrict__ outp = part + (size_t)c * T;

    for (int i = 0; i < perWave; i += 16) {
        const int t = t0 + i + g;
        if (t >= T) continue;
        const int i0 = trip[3 * t + 0];
        const int i1 = trip[3 * t + 1];
        const int i2 = trip[3 * t + 2];

        const float* A = embc + (size_t)i0 * D;
        const float* P = embc + (size_t)i1 * D;
        const float* N = embc + (size_t)i2 * D;

        const float4 a0 = *(const float4*)(A);
        const float4 a1 = *(const float4*)(A + 16);
        const float4 a2 = *(const float4*)(A + 32);
        const float4 a3 = *(const float4*)(A + 48);
        const float4 p0 = *(const float4*)(P);
        const float4 p1 = *(const float4*)(P + 16);
        const float4 p2 = *(const float4*)(P + 32);
        const float4 p3 = *(const float4*)(P + 48);
        const float4 n0 = *(const float4*)(N);
        const float4 n1 = *(const float4*)(N + 16);
        const float4 n2 = *(const float4*)(N + 32);
        const float4 n3 = *(const float4*)(N + 48);

        float ap = dot4(a0, p0) + dot4(a1, p1) + dot4(a2, p2) + dot4(a3, p3);
        float an = dot4(a0, n0) + dot4(a1, n1) + dot4(a2, n2) + dot4(a3, n3);

        // reduce across the 4 lanes of the group
        ap += __shfl_xor(ap, 1);
        ap += __shfl_xor(ap, 2);
        an += __shfl_xor(an, 1);
        an += __shfl_xor(an, 2);

        if (sub == 0) outp[t] = make_float2(ap, an);
    }
}

// ---------------- pass 2: combine chunks, clip, exp, block-reduce ----------------
constexpr int P2_BLOCKS  = 512;
constexpr int P2_THREADS = 256;

__global__ __launch_bounds__(P2_THREADS) void p2_combine(
    const float2* __restrict__ part, int T,
    float* __restrict__ bpart /* [P2_BLOCKS*3] */) {

    const int t = blockIdx.x * P2_THREADS + threadIdx.x;

    float ap = 0.f, an = 0.f;
    if (t < T) {
        #pragma unroll
        for (int c = 0; c < NCHUNK; ++c) {
            const float2 v = part[(size_t)c * T + t];
            ap += v.x; an += v.y;
        }
    }
    ap = fminf(fmaxf(ap, -1.0f), 1.0f);
    an = fminf(fmaxf(an, -1.0f), 1.0f);

    float s_loss = (t < T) ? __expf((an - ap) * MARGIN_INV) : 0.f;
    float s_ap   = (t < T) ? (1.0f - ap) : 0.f;
    float s_an   = (t < T) ? (1.0f - an) : 0.f;

    #pragma unroll
    for (int off = 32; off; off >>= 1) {
        s_loss += __shfl_xor(s_loss, off);
        s_ap   += __shfl_xor(s_ap, off);
        s_an   += __shfl_xor(s_an, off);
    }
    __shared__ float red[4][3];
    const int lane = threadIdx.x & 63, wave = threadIdx.x >> 6;
    if (lane == 0) { red[wave][0] = s_loss; red[wave][1] = s_ap; red[wave][2] = s_an; }
    __syncthreads();
    if (threadIdx.x == 0) {
        float a = 0.f, b = 0.f, cc = 0.f;
        #pragma unroll
        for (int w = 0; w < 4; ++w) { a += red[w][0]; b += red[w][1]; cc += red[w][2]; }
        bpart[blockIdx.x * 3 + 0] = a;
        bpart[blockIdx.x * 3 + 1] = b;
        bpart[blockIdx.x * 3 + 2] = cc;
    }
}

// ---------------- pass 3: final reduce ----------------
__global__ __launch_bounds__(256) void p3_final(
    const float* __restrict__ bpart, int nblocks, int T,
    float* __restrict__ out) {

    const int tid = threadIdx.x;
    float a = 0.f, b = 0.f, c = 0.f;
    for (int i = tid; i < nblocks; i += 256) {
        a += bpart[3 * i + 0];
        b += bpart[3 * i + 1];
        c += bpart[3 * i + 2];
    }
    #pragma unroll
    for (int off = 32; off; off >>= 1) {
        a += __shfl_xor(a, off);
        b += __shfl_xor(b, off);
        c += __shfl_xor(c, off);
    }
    __shared__ float red[4][3];
    const int lane = tid & 63, wave = tid >> 6;
    if (lane == 0) { red[wave][0] = a; red[wave][1] = b; red[wave][2] = c; }
    __syncthreads();
    if (tid == 0) {
        float A = 0.f, B = 0.f, C = 0.f;
        #pragma unroll
        for (int w = 0; w < 4; ++w) { A += red[w][0]; B += red[w][1]; C += red[w][2]; }
        const float inv = 1.0f / (float)T;
        out[0] = A * inv;
        out[1] = B * inv;
        out[2] = C * inv;
    }
}

// ---------------- fallback (proven R2 kernel) ----------------
constexpr int FB_BLOCKS  = 2048;
constexpr int FB_THREADS = 256;
constexpr int FB_WPB     = FB_THREADS / 64;
constexpr int FB_TOTALW  = FB_BLOCKS * FB_WPB;

__global__ __launch_bounds__(FB_THREADS) void fb_main(
    const float* __restrict__ emb, const int* __restrict__ trip, int T,
    float* __restrict__ partials) {

    const int lane  = threadIdx.x & 63;
    const int wave  = threadIdx.x >> 6;
    const int gwave = blockIdx.x * FB_WPB + wave;

    float s_loss = 0.f, s_ap = 0.f, s_an = 0.f;
    for (int t = gwave; t < T; t += FB_TOTALW) {
        const int i0 = trip[3 * t + 0];
        const int i1 = trip[3 * t + 1];
        const int i2 = trip[3 * t + 2];
        const float4* a4 = (const float4*)(emb + (size_t)i0 * D) + (lane << 1);
        const float4* p4 = (const float4*)(emb + (size_t)i1 * D) + (lane << 1);
        const float4* n4 = (const float4*)(emb + (size_t)i2 * D) + (lane << 1);
        const float4 a0 = a4[0], a1 = a4[1];
        const float4 p0 = p4[0], p1 = p4[1];
        const float4 n0 = n4[0], n1 = n4[1];
        float ap = dot4(a0, p0) + dot4(a1, p1);
        float an = dot4(a0, n0) + dot4(a1, n1);
        #pragma unroll
        for (int off = 32; off; off >>= 1) { ap += __shfl_xor(ap, off); an += __shfl_xor(an, off); }
        ap = fminf(fmaxf(ap, -1.0f), 1.0f);
        an = fminf(fmaxf(an, -1.0f), 1.0f);
        s_loss += __expf((an - ap) * MARGIN_INV);
        s_ap   += 1.0f - ap;
        s_an   += 1.0f - an;
    }
    __shared__ float red[FB_WPB][3];
    if (lane == 0) { red[wave][0] = s_loss; red[wave][1] = s_ap; red[wave][2] = s_an; }
    __syncthreads();
    if (threadIdx.x == 0) {
        float a = 0.f, b = 0.f, c = 0.f;
        #pragma unroll
        for (int w = 0; w < FB_WPB; ++w) { a += red[w][0]; b += red[w][1]; c += red[w][2]; }
        partials[blockIdx.x * 3 + 0] = a;
        partials[blockIdx.x * 3 + 1] = b;
        partials[blockIdx.x * 3 + 2] = c;
    }
}

extern "C" void kernel_launch(void* const* d_in, const int* in_sizes, int n_in,
                              void* d_out, int out_size, void* d_ws, size_t ws_size,
                              hipStream_t stream) {
    const float* emb  = (const float*)d_in[0];
    const int*   trip = (const int*)d_in[1];
    float* out = (float*)d_out;
    const int T = in_sizes[1] / 3;     // 131072

    const size_t partBytes = (size_t)NCHUNK * T * sizeof(float2);   // 8 MB
    const size_t needed = partBytes + P2_BLOCKS * 3 * sizeof(float);

    if (ws_size >= needed) {
        float2* part  = (float2*)d_ws;
        float*  bpart = (float*)((char*)d_ws + partBytes);
        p1_chunk_dots<<<P1_BLOCKS, P1_THREADS, 0, stream>>>(emb, trip, T, part);
        p2_combine<<<P2_BLOCKS, P2_THREADS, 0, stream>>>(part, T, bpart);
        p3_final<<<1, 256, 0, stream>>>(bpart, P2_BLOCKS, T, out);
    } else {
        float* partials = (float*)d_ws;   // 24 KB
        fb_main<<<FB_BLOCKS, FB_THREADS, 0, stream>>>(emb, trip, T, partials);
        p3_final<<<1, 256, 0, stream>>>(partials, FB_BLOCKS, T, out);
    }
}